// Round 7
// baseline (130.382 us; speedup 1.0000x reference)
//
#include <hip/hip_runtime.h>
#include <hip/hip_bf16.h>

// Problem constants
#define BB 16
#define TT 2048
#define CC 128
#define HH 128
#define NQT128 16          // q tiles of 128 rows

typedef __bf16 bf16x8 __attribute__((ext_vector_type(8)));
typedef __bf16 bf16x4 __attribute__((ext_vector_type(4)));
typedef float  f32x4  __attribute__((ext_vector_type(4)));
typedef unsigned int u32x2 __attribute__((ext_vector_type(2)));

// ws layout (bf16 elems unless noted):
//   Qs  [b][tt16 128][ks 4][lane 64][j 8]   (exp2-domain scale folded)
//   Ks  [b][tt16 128][ks 4][lane 64][j 8]   (32-key tile = 8 KB contig)
//   Vs  [b][t32 64][h16 8][lane 64][j 8]    (32-key tile = 8 KB contig)
//   Wbf 3*128*128 FRAGMENT-SWIZZLED: [which][blk16 8][ks 4][lane 64][j 8]
//   partial slots: bf16 o[128*128] (32768 B) + float l[128] (512 B)
#define BTH       ((size_t)BB * TT * HH)
#define WBF_OFF   (3 * BTH)
#define PARTIAL_OFF_BYTES (3 * BTH * 2 + 3 * 128 * 128 * 2)
#define SLOT_BYTES 33280
#define SLOT_L_OFF 32768

static __device__ __forceinline__ bf16x8 load_cvt8(const float* p) {
    float4 a = *(const float4*)p;
    float4 b = *(const float4*)(p + 4);
    bf16x8 r;
    r[0] = (__bf16)a.x; r[1] = (__bf16)a.y; r[2] = (__bf16)a.z; r[3] = (__bf16)a.w;
    r[4] = (__bf16)b.x; r[5] = (__bf16)b.y; r[6] = (__bf16)b.z; r[7] = (__bf16)b.w;
    return r;
}

// async global->LDS, 16 B/lane: data lands at lds_base + lane*16
static __device__ __forceinline__ void load_lds16(const void* g, void* l) {
    __builtin_amdgcn_global_load_lds(
        (const __attribute__((address_space(1))) unsigned int*)g,
        (__attribute__((address_space(3))) unsigned int*)l, 16, 0, 0);
}

// ---------------------------------------------------------------------------
// W pre-convert + FRAGMENT SWIZZLE (proj W loads become lane*16B coalesced).
// ---------------------------------------------------------------------------
__global__ __launch_bounds__(256) void wcvt_kernel(
    const float* __restrict__ Wq, const float* __restrict__ Wk,
    const float* __restrict__ Wv, __bf16* __restrict__ wbf)
{
    int idx = blockIdx.x * 256 + threadIdx.x;          // < 6144
    int which = idx >> 11;
    int rem = idx & 2047;
    int blk = rem >> 8;
    int r2  = rem & 255;
    int ks   = r2 >> 6;
    int lane = r2 & 63;
    int quad = lane >> 4, l16 = lane & 15;
    const float* src = (which == 0) ? Wq : (which == 1) ? Wk : Wv;
    float sc = (which == 0) ? (0.08838834764831845f * 1.4426950408889634f) : 1.0f;
    const float* p = src + (size_t)(blk * 16 + l16) * CC + ks * 32 + quad * 8;
    bf16x8 v;
    #pragma unroll
    for (int j = 0; j < 8; ++j) v[j] = (__bf16)(p[j] * sc);
    *(bf16x8*)(wbf + (size_t)which * 16384 + (((size_t)(blk * 4 + ks)) << 9) + lane * 8) = v;
}

// ---------------------------------------------------------------------------
// Projection, fully coalesced (x via padded LDS, W fragment-swizzled).
// ---------------------------------------------------------------------------
#define TR_QK 132
#define TR_V  68

__global__ __launch_bounds__(256) void proj_kernel(
    const float* __restrict__ x, __bf16* __restrict__ ws)
{
    __shared__ float  xs[64 * 132];
    __shared__ __bf16 tr[128 * TR_V];

    const int lane = threadIdx.x & 63;
    const int wave = threadIdx.x >> 6;
    const int quad = lane >> 4;
    const int l16  = lane & 15;
    const int tid  = threadIdx.x;
    const int m0 = blockIdx.x * 64;
    const int b  = m0 / TT;
    const int t0 = m0 % TT;

    const __bf16* Wbf = ws + WBF_OFF;
    __bf16* Qs = ws;
    __bf16* Ks = ws + BTH;
    __bf16* Vs = ws + 2 * BTH;

    const float* xg = x + (size_t)m0 * CC;
    #pragma unroll
    for (int t = 0; t < 8; ++t) {
        int f = t * 256 + tid;
        int row = f >> 5, c4 = f & 31;
        float4 v = *(const float4*)(xg + (size_t)f * 4);
        *(float4*)(&xs[row * 132 + c4 * 4]) = v;
    }
    __syncthreads();

    bf16x8 xf[4];
    #pragma unroll
    for (int ks = 0; ks < 4; ++ks)
        xf[ks] = load_cvt8(&xs[(wave * 16 + l16) * 132 + ks * 32 + quad * 8]);

    #pragma unroll
    for (int which = 0; which < 2; ++which) {
        const __bf16* Wb = Wbf + (size_t)which * 16384;
        __bf16* dst = which ? Ks : Qs;
        #pragma unroll
        for (int nt = 0; nt < 8; ++nt) {
            f32x4 acc = {0.f, 0.f, 0.f, 0.f};
            #pragma unroll
            for (int ks = 0; ks < 4; ++ks) {
                bf16x8 wf = *(const bf16x8*)(Wb + (((size_t)(nt * 4 + ks)) << 9) + lane * 8);
                acc = __builtin_amdgcn_mfma_f32_16x16x32_bf16(xf[ks], wf, acc, 0, 0, 0);
            }
            #pragma unroll
            for (int r = 0; r < 4; ++r)
                tr[(wave * 16 + quad * 4 + r) * TR_QK + nt * 16 + l16] = (__bf16)acc[r];
        }
        asm volatile("s_waitcnt lgkmcnt(0)" ::: "memory");
        #pragma unroll
        for (int ks = 0; ks < 4; ++ks) {
            const __bf16* p = &tr[(wave * 16 + l16) * TR_QK + ks * 32 + quad * 8];
            uint2 lo = *(const uint2*)p;
            uint2 hi = *(const uint2*)(p + 4);
            uint4 v; v.x = lo.x; v.y = lo.y; v.z = hi.x; v.w = hi.y;
            __bf16* o = dst + (((size_t)(b * 128 + t0 / 16 + wave) * 4 + ks) << 9) + lane * 8;
            *(uint4*)o = v;
        }
        asm volatile("s_waitcnt lgkmcnt(0)" ::: "memory");
    }

    __syncthreads();
    const __bf16* Wv = Wbf + 2 * 16384;
    #pragma unroll
    for (int msub = 0; msub < 8; ++msub) {
        f32x4 acc = {0.f, 0.f, 0.f, 0.f};
        #pragma unroll
        for (int ks = 0; ks < 4; ++ks) {
            bf16x8 wf = *(const bf16x8*)(Wv + (((size_t)(msub * 4 + ks)) << 9) + lane * 8);
            acc = __builtin_amdgcn_mfma_f32_16x16x32_bf16(wf, xf[ks], acc, 0, 0, 0);
        }
        #pragma unroll
        for (int r = 0; r < 4; ++r)
            tr[(msub * 16 + quad * 4 + r) * TR_V + wave * 16 + l16] = (__bf16)acc[r];
    }
    __syncthreads();
    #pragma unroll
    for (int i = 0; i < 4; ++i) {
        int t32 = i >> 1;
        int h16 = wave * 2 + (i & 1);
        const __bf16* p = &tr[(h16 * 16 + l16) * TR_V + t32 * 32 + quad * 8];
        uint2 lo = *(const uint2*)p;
        uint2 hi = *(const uint2*)(p + 4);
        uint4 v; v.x = lo.x; v.y = lo.y; v.z = hi.x; v.w = hi.y;
        __bf16* o = Vs + (((size_t)(b * 64 + t0 / 32 + t32) * 8 + h16) << 9) + lane * 8;
        *(uint4*)o = v;
    }
}

// ---------------------------------------------------------------------------
// Split-K flash attention, 32-key tiles, double-buffered LDS staging.
// SINGLE-BARRIER loop (m248 2-phase recipe): per tile
//   { STAGE(tt+1 -> other buf); compute(buf cur); vmcnt(0); s_barrier }
// with a prologue {STAGE; vmcnt(0); barrier}. Safety: each wave's ds_reads
// of buf cur are drained before its consuming MFMAs (compiler waitcnts),
// which precede the shared end-barrier; the next iteration's STAGE into
// that buffer comes after the barrier -> race-free with HALF the barriers.
// DMA drain (vmcnt 0) sits AFTER ~600 cycles of compute -> effectively free.
//  - swapped QK^T (mfma(K,Q) -> S^T); P redistribution in-register via
//    permlane32_swap + permlane16_swap (no P LDS round-trip).
//  - s_setprio(1) around MFMA clusters; early V half-prefetch.
//  - plain __launch_bounds__(256): a forced waves/EU cap caused accumulator
//    spills in round 2 (176 MB scratch traffic). VGPR must stay <= ~128.
// Removed (round-5 lesson): fused reduction via device-scope __threadfence
// (each fence = L2 writeback on non-coherent 8-XCD chip; 4x attn time).
// ---------------------------------------------------------------------------
__global__ __launch_bounds__(256) void attn_kernel(
    const __bf16* __restrict__ ws, char* __restrict__ po,
    float* __restrict__ outp, int G, int SPB, int direct)
{
    __shared__ __bf16 ldsK[2][4096];            // 2 x 8 KB
    __shared__ __bf16 ldsV[2][4096];            // 2 x 8 KB  -> total 32768 B

    const int lane = threadIdx.x & 63;
    const int wave = threadIdx.x >> 6;
    const int quad = lane >> 4;
    const int l16  = lane & 15;
    const int lane8 = lane * 8;
    const int lo16 = lane * 16;

    const int lin = blockIdx.x;
    const int b  = (lin & 7) * 2 + ((lin >> 3) & 1);   // XCD-clustered batch
    const int s  = SPB - 1 - (lin >> 4);               // heavy slots first

    // slot -> (qt, seg) in 64-key units, then convert to 32-key tiles
    int acc = 0, qt = 0, seg = 0;
    for (int q = 0; q < NQT128; ++q) {
        int c = (2 * (q + 1) + G - 1) / G;
        if (s < acc + c) { qt = q; seg = s - acc; break; }
        acc += c;
    }
    const int kt0 = seg * G;
    int kt1 = 2 * (qt + 1);
    if (kt0 + G < kt1) kt1 = kt0 + G;
    const int segs_qt = (2 * (qt + 1) + G - 1) / G;
    const int dwrite = direct | (segs_qt == 1);

    const int tt0 = kt0 * 2, tt1 = kt1 * 2;            // 32-key tiles (even count)
    const int qw = qt * 128 + wave * 32;               // wave's first q row
    int ttw = (qw + 63) >> 5;                          // wave causal clamp
    if (ttw > tt1) ttw = tt1;

    const __bf16* Qs = ws;
    const __bf16* Ks = ws + BTH;
    const __bf16* Vs = ws + 2 * BTH;

    bf16x8 qf[2][4];
    #pragma unroll
    for (int m = 0; m < 2; ++m)
        #pragma unroll
        for (int ks = 0; ks < 4; ++ks)
            qf[m][ks] = *(const bf16x8*)(Qs + (((size_t)(b * 128 + qt * 8 + wave * 2 + m) * 4 + ks) << 9) + lane8);

    float l_r[2] = {0.f, 0.f};
    f32x4 o[2][8];
    #pragma unroll
    for (int m = 0; m < 2; ++m)
        #pragma unroll
        for (int h8 = 0; h8 < 8; ++h8) o[m][h8] = (f32x4){0.f, 0.f, 0.f, 0.f};

    // incremental staging pointers: each 32-key tile is 8 KB contiguous
    const char* kg = (const char*)Ks + (size_t)b * 524288 + wave * 2048 + lo16;
    const char* vg = (const char*)Vs + (size_t)b * 524288 + wave * 2048 + lo16;
    char* const dKa[2] = {(char*)ldsK[0] + wave * 2048, (char*)ldsK[1] + wave * 2048};
    char* const dVa[2] = {(char*)ldsV[0] + wave * 2048, (char*)ldsV[1] + wave * 2048};

    #define STAGE(TTv, KD, VD)                                  \
        do {                                                    \
            size_t o_ = (size_t)(TTv) << 13;                    \
            load_lds16(kg + o_,        (KD));                   \
            load_lds16(kg + o_ + 1024, (KD) + 1024);            \
            load_lds16(vg + o_,        (VD));                   \
            load_lds16(vg + o_ + 1024, (VD) + 1024);            \
        } while (0)

    // prologue: first tile staged and visible to all waves
    STAGE(tt0, dKa[0], dVa[0]);
    asm volatile("s_waitcnt vmcnt(0)" ::: "memory");
    __builtin_amdgcn_s_barrier();

    for (int tp = tt0; tp < tt1; tp += 2) {
        #pragma unroll
        for (int hh = 0; hh < 2; ++hh) {
            const int tt = tp + hh;
            // issue next-tile DMA; it flies under this tile's compute
            if (tt + 1 < tt1) STAGE(tt + 1, dKa[hh ^ 1], dVa[hh ^ 1]);

            if (tt < ttw) {
                const char* lk = (const char*)ldsK[hh];
                const char* lv = (const char*)ldsV[hh];

                // early V prefetch (first PV half): latency hides under QK/exp2
                bf16x8 vrA[4];
                #pragma unroll
                for (int h = 0; h < 4; ++h)
                    vrA[h] = *(const bf16x8*)(lv + (h << 10) + lo16);

                // ---- S^T = K Q^T (swapped: lane holds 4 consecutive keys / q)
                f32x4 s2[2][2];
                #pragma unroll
                for (int nsub = 0; nsub < 2; ++nsub) {
                    bf16x8 kfr[4];
                    #pragma unroll
                    for (int ks = 0; ks < 4; ++ks)
                        kfr[ks] = *(const bf16x8*)(lk + ((nsub * 4 + ks) << 10) + lo16);
                    __builtin_amdgcn_s_setprio(1);
                    #pragma unroll
                    for (int m = 0; m < 2; ++m) {
                        f32x4 a2 = {0.f, 0.f, 0.f, 0.f};
                        #pragma unroll
                        for (int ks = 0; ks < 4; ++ks)
                            a2 = __builtin_amdgcn_mfma_f32_16x16x32_bf16(kfr[ks], qf[m][ks], a2, 0, 0, 0);
                        s2[m][nsub] = a2;
                    }
                    __builtin_amdgcn_s_setprio(0);
                }

                const int k0 = tt * 32;
                // ---- mask + exp2 + lane-local l; pack P into dwords ----------
                unsigned int du[2][2][2];
                #pragma unroll
                for (int m = 0; m < 2; ++m) {
                    const int qrow = qw + m * 16 + l16;     // this lane's q row
                    if (k0 + 31 > qw + m * 16) {            // boundary tile (uniform)
                        #pragma unroll
                        for (int nsub = 0; nsub < 2; ++nsub) {
                            const int kb = k0 + nsub * 16 + quad * 4;
                            union { bf16x4 v; unsigned int u[2]; } cv;
                            #pragma unroll
                            for (int r = 0; r < 4; ++r) {
                                float sv = (kb + r > qrow) ? -3e38f : s2[m][nsub][r];
                                float p = __builtin_amdgcn_exp2f(sv);
                                l_r[m] += p;
                                cv.v[r] = (__bf16)p;
                            }
                            du[m][nsub][0] = cv.u[0];
                            du[m][nsub][1] = cv.u[1];
                        }
                    } else {
                        #pragma unroll
                        for (int nsub = 0; nsub < 2; ++nsub) {
                            union { bf16x4 v; unsigned int u[2]; } cv;
                            #pragma unroll
                            for (int r = 0; r < 4; ++r) {
                                float p = __builtin_amdgcn_exp2f(s2[m][nsub][r]);
                                l_r[m] += p;
                                cv.v[r] = (__bf16)p;
                            }
                            du[m][nsub][0] = cv.u[0];
                            du[m][nsub][1] = cv.u[1];
                        }
                    }
                }

                // ---- P: C-layout -> A-layout fully in-register ---------------
                bf16x8 pf[2];
                #pragma unroll
                for (int m = 0; m < 2; ++m) {
                    union { unsigned int u[4]; bf16x8 v; } cc;
                    #pragma unroll
                    for (int h = 0; h < 2; ++h) {
                        u32x2 t1 = __builtin_amdgcn_permlane32_swap(
                            du[m][0][h], du[m][1][h], false, false);
                        u32x2 t2 = __builtin_amdgcn_permlane16_swap(
                            t1[0], t1[1], false, false);
                        cc.u[h]     = t2[0];   // dword j = h     (q0_old=0)
                        cc.u[2 + h] = t2[1];   // dword j = 2 + h (q0_old=1)
                    }
                    pf[m] = cc.v;
                }

                // ---- O += P V (k = 32), two halves; vrA regs reused ----------
                __builtin_amdgcn_s_setprio(1);
                #pragma unroll
                for (int h = 0; h < 4; ++h)
                    #pragma unroll
                    for (int m = 0; m < 2; ++m)
                        o[m][h] = __builtin_amdgcn_mfma_f32_16x16x32_bf16(pf[m], vrA[h], o[m][h], 0, 0, 0);
                __builtin_amdgcn_s_setprio(0);
                #pragma unroll
                for (int h = 0; h < 4; ++h)
                    vrA[h] = *(const bf16x8*)(lv + ((4 + h) << 10) + lo16);
                __builtin_amdgcn_s_setprio(1);
                #pragma unroll
                for (int h = 0; h < 4; ++h)
                    #pragma unroll
                    for (int m = 0; m < 2; ++m)
                        o[m][4 + h] = __builtin_amdgcn_mfma_f32_16x16x32_bf16(pf[m], vrA[h], o[m][4 + h], 0, 0, 0);
                __builtin_amdgcn_s_setprio(0);
            }
            // single barrier: next-tile DMA drained; all waves' reads of buf hh
            // already retired (their consuming MFMAs precede this point).
            asm volatile("s_waitcnt vmcnt(0)" ::: "memory");
            __builtin_amdgcn_s_barrier();
        }
    }
    #undef STAGE

    // l reduction across quads (row l16's sum becomes uniform over quads)
    #pragma unroll
    for (int m = 0; m < 2; ++m) {
        l_r[m] += __shfl_xor(l_r[m], 16, 64);
        l_r[m] += __shfl_xor(l_r[m], 32, 64);
    }

    if (dwrite) {
        #pragma unroll
        for (int m = 0; m < 2; ++m) {
            float inv[4];
            #pragma unroll
            for (int r = 0; r < 4; ++r)
                inv[r] = 1.0f / __shfl(l_r[m], (lane & 48) | (quad * 4 + r), 64);
            #pragma unroll
            for (int h8 = 0; h8 < 8; ++h8)
                #pragma unroll
                for (int r = 0; r < 4; ++r)
                    outp[(size_t)(b * TT + qw + m * 16 + quad * 4 + r) * HH + h8 * 16 + l16] = o[m][h8][r] * inv[r];
        }
    } else {
        char* slot = po + (size_t)(b * SPB + s) * SLOT_BYTES;
        __bf16* slot_o = (__bf16*)slot;
        float*  slot_l = (float*)(slot + SLOT_L_OFF);
        #pragma unroll
        for (int m = 0; m < 2; ++m) {
            #pragma unroll
            for (int h8 = 0; h8 < 8; ++h8)
                #pragma unroll
                for (int r = 0; r < 4; ++r)
                    slot_o[(size_t)(wave * 32 + m * 16 + quad * 4 + r) * 128 + h8 * 16 + l16] = (__bf16)o[m][h8][r];
            if (quad == 0)
                slot_l[wave * 32 + m * 16 + l16] = l_r[m];
        }
    }
}

// ---------------------------------------------------------------------------
// Reduce: sum bf16 partial o + fp32 l over segments, normalize.
// XCD-AFFINITY: batch b's partials are written by attn blocks with
// lin&7 == b>>1; map blockIdx so id&7 matches -> partial reads hit the
// same XCD's L2 instead of round-tripping HBM.
// ---------------------------------------------------------------------------
__global__ __launch_bounds__(256) void reduce_kernel(
    const char* __restrict__ po, float* __restrict__ outp, int G, int SPB)
{
    __shared__ float lsum[32];
    const int id  = blockIdx.x;                 // 1024 blocks
    const int c   = id & 7;
    const int j   = id >> 3;                    // 0..127
    const int b   = c * 2 + (j >> 6);
    const int rem = j & 63;
    const int qt  = rem >> 2;
    const int qtr = rem & 3;
    const int tid = threadIdx.x;

    const int segs = (2 * (qt + 1) + G - 1) / G;
    if (segs == 1) return;

    int acc = 0;
    for (int qq = 0; qq < qt; ++qq) acc += (2 * (qq + 1) + G - 1) / G;
    const char* base = po + (size_t)(b * SPB + acc) * SLOT_BYTES;
    const int r0 = qtr * 32;

    if (tid < 32) {
        float v = 0.f;
        for (int sg = 0; sg < segs; ++sg)
            v += ((const float*)(base + (size_t)sg * SLOT_BYTES + SLOT_L_OFF))[r0 + tid];
        lsum[tid] = v;
    }
    __syncthreads();

    const int rsub = tid >> 4;
    const int cg   = tid & 15;
    float a[2][8];
    #pragma unroll
    for (int p = 0; p < 2; ++p)
        #pragma unroll
        for (int jj = 0; jj < 8; ++jj) a[p][jj] = 0.f;

    for (int sg = 0; sg < segs; ++sg) {
        const char* sb = base + (size_t)sg * SLOT_BYTES;
        #pragma unroll
        for (int p = 0; p < 2; ++p) {
            int row = r0 + rsub + p * 16;
            union { uint4 u; __bf16 h[8]; } v;
            v.u = *(const uint4*)(sb + ((size_t)row * 128 + cg * 8) * 2);
            #pragma unroll
            for (int jj = 0; jj < 8; ++jj) a[p][jj] += (float)v.h[jj];
        }
    }

    #pragma unroll
    for (int p = 0; p < 2; ++p) {
        int row = r0 + rsub + p * 16;
        float inv = 1.0f / lsum[rsub + p * 16];
        float* op = outp + (size_t)(b * TT + qt * 128 + row) * HH + cg * 8;
        float4 o0 = {a[p][0] * inv, a[p][1] * inv, a[p][2] * inv, a[p][3] * inv};
        float4 o1 = {a[p][4] * inv, a[p][5] * inv, a[p][6] * inv, a[p][7] * inv};
        *(float4*)op = o0;
        *(float4*)(op + 4) = o1;
    }
}

extern "C" void kernel_launch(void* const* d_in, const int* in_sizes, int n_in,
                              void* d_out, int out_size, void* d_ws, size_t ws_size,
                              hipStream_t stream)
{
    const float* x  = (const float*)d_in[0];
    const float* Wq = (const float*)d_in[1];
    const float* Wk = (const float*)d_in[2];
    const float* Wv = (const float*)d_in[3];
    __bf16* ws = (__bf16*)d_ws;
    float* out = (float*)d_out;
    char* po   = (char*)d_ws + PARTIAL_OFF_BYTES;

    int G = 0, SPB = 0, direct = 1;
    const int cand[5] = {4, 5, 6, 8, 16};
    for (int ci = 0; ci < 5; ++ci) {
        int g = cand[ci], spb = 0;
        for (int q = 0; q < NQT128; ++q) spb += (2 * (q + 1) + g - 1) / g;
        size_t need = PARTIAL_OFF_BYTES + (size_t)spb * BB * SLOT_BYTES;
        if (need <= ws_size) { G = g; SPB = spb; direct = 0; break; }
    }
    if (direct) { G = 2 * NQT128; SPB = NQT128; }

    wcvt_kernel<<<24, 256, 0, stream>>>(Wq, Wk, Wv, ws + WBF_OFF);
    proj_kernel<<<512, 256, 0, stream>>>(x, ws);
    attn_kernel<<<SPB * 16, 256, 0, stream>>>(ws, po, out, G, SPB, direct);
    if (!direct) {
        reduce_kernel<<<1024, 256, 0, stream>>>(po, out, G, SPB);
    }
}

// Round 8
// 127.062 us; speedup vs baseline: 1.0261x; 1.0261x over previous
//
#include <hip/hip_runtime.h>
#include <hip/hip_bf16.h>

// Problem constants
#define BB 16
#define TT 2048
#define CC 128
#define HH 128
#define NQT128 16          // q tiles of 128 rows

typedef __bf16 bf16x8 __attribute__((ext_vector_type(8)));
typedef __bf16 bf16x4 __attribute__((ext_vector_type(4)));
typedef float  f32x4  __attribute__((ext_vector_type(4)));
typedef unsigned int u32x2 __attribute__((ext_vector_type(2)));

// ws layout (bf16 elems unless noted):
//   Qs  [b][tt16 128][ks 4][lane 64][j 8]   (exp2-domain scale folded)
//   Ks  [b][tt16 128][ks 4][lane 64][j 8]   (32-key tile = 8 KB contig)
//   Vs  [b][t32 64][h16 8][lane 64][j 8]    (32-key tile = 8 KB contig; h-halves
//                                            are the two 4 KB halves of a tile)
//   Wbf 3*128*128 FRAGMENT-SWIZZLED: [which][blk16 8][ks 4][lane 64][j 8]
#define BTH       ((size_t)BB * TT * HH)
#define WBF_OFF   (3 * BTH)

static __device__ __forceinline__ bf16x8 load_cvt8(const float* p) {
    float4 a = *(const float4*)p;
    float4 b = *(const float4*)(p + 4);
    bf16x8 r;
    r[0] = (__bf16)a.x; r[1] = (__bf16)a.y; r[2] = (__bf16)a.z; r[3] = (__bf16)a.w;
    r[4] = (__bf16)b.x; r[5] = (__bf16)b.y; r[6] = (__bf16)b.z; r[7] = (__bf16)b.w;
    return r;
}

// async global->LDS, 16 B/lane: data lands at lds_base + lane*16
static __device__ __forceinline__ void load_lds16(const void* g, void* l) {
    __builtin_amdgcn_global_load_lds(
        (const __attribute__((address_space(1))) unsigned int*)g,
        (__attribute__((address_space(3))) unsigned int*)l, 16, 0, 0);
}

// ---------------------------------------------------------------------------
// W pre-convert + FRAGMENT SWIZZLE (proj W loads become lane*16B coalesced).
// ---------------------------------------------------------------------------
__global__ __launch_bounds__(256) void wcvt_kernel(
    const float* __restrict__ Wq, const float* __restrict__ Wk,
    const float* __restrict__ Wv, __bf16* __restrict__ wbf)
{
    int idx = blockIdx.x * 256 + threadIdx.x;          // < 6144
    int which = idx >> 11;
    int rem = idx & 2047;
    int blk = rem >> 8;
    int r2  = rem & 255;
    int ks   = r2 >> 6;
    int lane = r2 & 63;
    int quad = lane >> 4, l16 = lane & 15;
    const float* src = (which == 0) ? Wq : (which == 1) ? Wk : Wv;
    float sc = (which == 0) ? (0.08838834764831845f * 1.4426950408889634f) : 1.0f;
    const float* p = src + (size_t)(blk * 16 + l16) * CC + ks * 32 + quad * 8;
    bf16x8 v;
    #pragma unroll
    for (int j = 0; j < 8; ++j) v[j] = (__bf16)(p[j] * sc);
    *(bf16x8*)(wbf + (size_t)which * 16384 + (((size_t)(blk * 4 + ks)) << 9) + lane * 8) = v;
}

// ---------------------------------------------------------------------------
// Projection, fully coalesced (x via padded LDS, W fragment-swizzled).
// ---------------------------------------------------------------------------
#define TR_QK 132
#define TR_V  68

__global__ __launch_bounds__(256) void proj_kernel(
    const float* __restrict__ x, __bf16* __restrict__ ws)
{
    __shared__ float  xs[64 * 132];
    __shared__ __bf16 tr[128 * TR_V];

    const int lane = threadIdx.x & 63;
    const int wave = threadIdx.x >> 6;
    const int quad = lane >> 4;
    const int l16  = lane & 15;
    const int tid  = threadIdx.x;
    const int m0 = blockIdx.x * 64;
    const int b  = m0 / TT;
    const int t0 = m0 % TT;

    const __bf16* Wbf = ws + WBF_OFF;
    __bf16* Qs = ws;
    __bf16* Ks = ws + BTH;
    __bf16* Vs = ws + 2 * BTH;

    const float* xg = x + (size_t)m0 * CC;
    #pragma unroll
    for (int t = 0; t < 8; ++t) {
        int f = t * 256 + tid;
        int row = f >> 5, c4 = f & 31;
        float4 v = *(const float4*)(xg + (size_t)f * 4);
        *(float4*)(&xs[row * 132 + c4 * 4]) = v;
    }
    __syncthreads();

    bf16x8 xf[4];
    #pragma unroll
    for (int ks = 0; ks < 4; ++ks)
        xf[ks] = load_cvt8(&xs[(wave * 16 + l16) * 132 + ks * 32 + quad * 8]);

    #pragma unroll
    for (int which = 0; which < 2; ++which) {
        const __bf16* Wb = Wbf + (size_t)which * 16384;
        __bf16* dst = which ? Ks : Qs;
        #pragma unroll
        for (int nt = 0; nt < 8; ++nt) {
            f32x4 acc = {0.f, 0.f, 0.f, 0.f};
            #pragma unroll
            for (int ks = 0; ks < 4; ++ks) {
                bf16x8 wf = *(const bf16x8*)(Wb + (((size_t)(nt * 4 + ks)) << 9) + lane * 8);
                acc = __builtin_amdgcn_mfma_f32_16x16x32_bf16(xf[ks], wf, acc, 0, 0, 0);
            }
            #pragma unroll
            for (int r = 0; r < 4; ++r)
                tr[(wave * 16 + quad * 4 + r) * TR_QK + nt * 16 + l16] = (__bf16)acc[r];
        }
        asm volatile("s_waitcnt lgkmcnt(0)" ::: "memory");
        #pragma unroll
        for (int ks = 0; ks < 4; ++ks) {
            const __bf16* p = &tr[(wave * 16 + l16) * TR_QK + ks * 32 + quad * 8];
            uint2 lo = *(const uint2*)p;
            uint2 hi = *(const uint2*)(p + 4);
            uint4 v; v.x = lo.x; v.y = lo.y; v.z = hi.x; v.w = hi.y;
            __bf16* o = dst + (((size_t)(b * 128 + t0 / 16 + wave) * 4 + ks) << 9) + lane * 8;
            *(uint4*)o = v;
        }
        asm volatile("s_waitcnt lgkmcnt(0)" ::: "memory");
    }

    __syncthreads();
    const __bf16* Wv = Wbf + 2 * 16384;
    #pragma unroll
    for (int msub = 0; msub < 8; ++msub) {
        f32x4 acc = {0.f, 0.f, 0.f, 0.f};
        #pragma unroll
        for (int ks = 0; ks < 4; ++ks) {
            bf16x8 wf = *(const bf16x8*)(Wv + (((size_t)(msub * 4 + ks)) << 9) + lane * 8);
            acc = __builtin_amdgcn_mfma_f32_16x16x32_bf16(wf, xf[ks], acc, 0, 0, 0);
        }
        #pragma unroll
        for (int r = 0; r < 4; ++r)
            tr[(msub * 16 + quad * 4 + r) * TR_V + wave * 16 + l16] = (__bf16)acc[r];
    }
    __syncthreads();
    #pragma unroll
    for (int i = 0; i < 4; ++i) {
        int t32 = i >> 1;
        int h16 = wave * 2 + (i & 1);
        const __bf16* p = &tr[(h16 * 16 + l16) * TR_V + t32 * 32 + quad * 8];
        uint2 lo = *(const uint2*)p;
        uint2 hi = *(const uint2*)(p + 4);
        uint4 v; v.x = lo.x; v.y = lo.y; v.z = hi.x; v.w = hi.y;
        __bf16* o = Vs + (((size_t)(b * 64 + t0 / 32 + t32) * 8 + h16) << 9) + lane * 8;
        *(uint4*)o = v;
    }
}

// ---------------------------------------------------------------------------
// BALANCED-PAIR flash attention — NO SPLIT-K, NO PARTIALS, NO REDUCE KERNEL.
// Each block owns complete q-rows and writes normalized output directly.
// Decomposition: pair q-tile i with q-tile 15-i (chain 4(i+1)+4(16-i)=68
// 32-key tiles, constant) x h-half (V cols; QK recomputed per half) x m-half
// (q rows 0-63 / 64-127 of each tile; chains 64/68, near-balanced):
//   8 pairs x 2 h x 2 m x 16 batches = 512 blocks (2/CU), 4 waves,
//   16 q-rows per wave (single m fragment).
// 64-key barrier intervals: stage {2 K tiles (16KB) + 2 V h-halves (8KB)}
// per interval, double-buffered (48 KB LDS), single barrier per interval
// (round-7 scheme), 33-35 intervals per block.
//  - swapped QK^T (mfma(K,Q) -> S^T); P redistribution in-register via
//    permlane32_swap + permlane16_swap.
//  - plain __launch_bounds__(256): forced waves/EU caps cause accumulator
//    spills (round-2 lesson: 176 MB scratch traffic).
//  - no device-scope fences anywhere (round-5 lesson).
// ---------------------------------------------------------------------------
__global__ __launch_bounds__(256) void attn_kernel(
    const __bf16* __restrict__ ws, float* __restrict__ outp)
{
    __shared__ char ldsBuf[2][24576];   // per buffer: K 2x8KB @0, V-half 2x4KB @16384

    const int lane = threadIdx.x & 63;
    const int wave = threadIdx.x >> 6;
    const int quad = lane >> 4;
    const int l16  = lane & 15;
    const int lane8 = lane * 8;
    const int lo16 = lane * 16;

    const int lin = blockIdx.x;                        // 512 blocks
    const int b   = (lin & 7) * 2 + ((lin >> 3) & 1);  // XCD-clustered batch
    const int rest = lin >> 4;                          // 0..31
    const int pid  = rest & 7;                          // pair 0..7
    const int hh0  = (rest >> 3) & 1;                   // head half
    const int mh   = 1 - (rest >> 4);                   // m-half (heavy mh=1 first)

    const __bf16* Qs = ws;
    const __bf16* Ks = ws + BTH;
    const __bf16* Vs = ws + 2 * BTH;

    // staging pointers (per-wave chunk bases)
    const char* kg = (const char*)Ks + (size_t)b * 524288 + wave * 4096 + lo16;
    const char* vg = (const char*)Vs + (size_t)b * 524288 + hh0 * 4096 + wave * 1024 + lo16;

    // stage one 64-key step j into buffer BUF: K 16KB (4 chunks/wave) + V 8KB
    #define STAGE64(J, BUF)                                                     \
        do {                                                                    \
            char* dK_ = ldsBuf[BUF] + wave * 4096;                              \
            char* dV_ = ldsBuf[BUF] + 16384 + wave * 1024;                      \
            const char* sk_ = kg + (size_t)(J) * 16384;                         \
            _Pragma("unroll")                                                   \
            for (int c_ = 0; c_ < 4; ++c_)                                      \
                load_lds16(sk_ + c_ * 1024, dK_ + c_ * 1024);                   \
            _Pragma("unroll")                                                   \
            for (int h_ = 0; h_ < 2; ++h_)                                      \
                load_lds16(vg + (size_t)(2 * (J) + h_) * 8192, dV_ + h_ * 4096);\
        } while (0)

    #pragma unroll 1
    for (int pass = 0; pass < 2; ++pass) {
        const int qt = pass ? (15 - pid) : pid;
        const int qw = qt * 128 + mh * 64 + wave * 16;     // wave's 16 q rows
        const int ttw = (qw >> 5) + 1;                     // wave causal clamp (32-key tiles)
        const int nj  = 2 * qt + mh + 1;                   // 64-key intervals

        // Q fragments (single m)
        bf16x8 qf[4];
        #pragma unroll
        for (int ks = 0; ks < 4; ++ks)
            qf[ks] = *(const bf16x8*)(Qs + (((size_t)(b * 128 + qt * 8 + mh * 4 + wave) * 4 + ks) << 9) + lane8);

        float l_r = 0.f;
        f32x4 o[4];
        #pragma unroll
        for (int h8 = 0; h8 < 4; ++h8) o[h8] = (f32x4){0.f, 0.f, 0.f, 0.f};

        STAGE64(0, 0);
        asm volatile("s_waitcnt vmcnt(0)" ::: "memory");
        __builtin_amdgcn_s_barrier();

        for (int j = 0; j < nj; ++j) {
            const int cur = j & 1;
            if (j + 1 < nj) STAGE64(j + 1, cur ^ 1);       // DMA flies under compute

            #pragma unroll
            for (int half = 0; half < 2; ++half) {
                const int tt = 2 * j + half;
                if (tt >= ttw) continue;
                const char* lk = ldsBuf[cur] + half * 8192;
                const char* lv = ldsBuf[cur] + 16384 + half * 4096;

                // ---- S^T = K Q^T (lane holds 4 consecutive keys for q=l16) --
                f32x4 s2[2];
                #pragma unroll
                for (int nsub = 0; nsub < 2; ++nsub) {
                    bf16x8 kfr[4];
                    #pragma unroll
                    for (int ks = 0; ks < 4; ++ks)
                        kfr[ks] = *(const bf16x8*)(lk + ((nsub * 4 + ks) << 10) + lo16);
                    f32x4 a2 = {0.f, 0.f, 0.f, 0.f};
                    __builtin_amdgcn_s_setprio(1);
                    #pragma unroll
                    for (int ks = 0; ks < 4; ++ks)
                        a2 = __builtin_amdgcn_mfma_f32_16x16x32_bf16(kfr[ks], qf[ks], a2, 0, 0, 0);
                    __builtin_amdgcn_s_setprio(0);
                    s2[nsub] = a2;
                }

                const int k0 = tt * 32;
                // ---- mask + exp2 + lane-local l; pack P into dwords --------
                unsigned int du[2][2];
                const int qrow = qw + l16;
                if (k0 + 31 > qw) {                        // boundary tile (uniform)
                    #pragma unroll
                    for (int nsub = 0; nsub < 2; ++nsub) {
                        const int kb = k0 + nsub * 16 + quad * 4;
                        union { bf16x4 v; unsigned int u[2]; } cv;
                        #pragma unroll
                        for (int r = 0; r < 4; ++r) {
                            float sv = (kb + r > qrow) ? -3e38f : s2[nsub][r];
                            float p = __builtin_amdgcn_exp2f(sv);
                            l_r += p;
                            cv.v[r] = (__bf16)p;
                        }
                        du[nsub][0] = cv.u[0];
                        du[nsub][1] = cv.u[1];
                    }
                } else {
                    #pragma unroll
                    for (int nsub = 0; nsub < 2; ++nsub) {
                        union { bf16x4 v; unsigned int u[2]; } cv;
                        #pragma unroll
                        for (int r = 0; r < 4; ++r) {
                            float p = __builtin_amdgcn_exp2f(s2[nsub][r]);
                            l_r += p;
                            cv.v[r] = (__bf16)p;
                        }
                        du[nsub][0] = cv.u[0];
                        du[nsub][1] = cv.u[1];
                    }
                }

                // ---- P: C-layout -> A-layout fully in-register -------------
                bf16x8 pf;
                {
                    union { unsigned int u[4]; bf16x8 v; } cc;
                    #pragma unroll
                    for (int h = 0; h < 2; ++h) {
                        u32x2 t1 = __builtin_amdgcn_permlane32_swap(
                            du[0][h], du[1][h], false, false);
                        u32x2 t2 = __builtin_amdgcn_permlane16_swap(
                            t1[0], t1[1], false, false);
                        cc.u[h]     = t2[0];
                        cc.u[2 + h] = t2[1];
                    }
                    pf = cc.v;
                }

                // ---- O += P V (k = 32) over this block's 4 h16 columns -----
                __builtin_amdgcn_s_setprio(1);
                #pragma unroll
                for (int h8 = 0; h8 < 4; ++h8) {
                    bf16x8 v0 = *(const bf16x8*)(lv + (h8 << 10) + lo16);
                    o[h8] = __builtin_amdgcn_mfma_f32_16x16x32_bf16(pf, v0, o[h8], 0, 0, 0);
                }
                __builtin_amdgcn_s_setprio(0);
            }
            // single barrier: next-step DMA drained; all waves' LDS reads of
            // buf cur retired (their consuming MFMAs precede this point).
            asm volatile("s_waitcnt vmcnt(0)" ::: "memory");
            __builtin_amdgcn_s_barrier();
        }

        // ---- normalize + direct write (per-wave; no block sync needed) -----
        l_r += __shfl_xor(l_r, 16, 64);
        l_r += __shfl_xor(l_r, 32, 64);
        float inv[4];
        #pragma unroll
        for (int r = 0; r < 4; ++r)
            inv[r] = 1.0f / __shfl(l_r, (lane & 48) | (quad * 4 + r), 64);
        #pragma unroll
        for (int h8 = 0; h8 < 4; ++h8)
            #pragma unroll
            for (int r = 0; r < 4; ++r)
                outp[(size_t)(b * TT + qw + quad * 4 + r) * HH + hh0 * 64 + h8 * 16 + l16] = o[h8][r] * inv[r];
        // next pass's prologue STAGE is safe: the last interval's end-barrier
        // guaranteed all waves' reads of both buffers completed.
    }
    #undef STAGE64
}

extern "C" void kernel_launch(void* const* d_in, const int* in_sizes, int n_in,
                              void* d_out, int out_size, void* d_ws, size_t ws_size,
                              hipStream_t stream)
{
    const float* x  = (const float*)d_in[0];
    const float* Wq = (const float*)d_in[1];
    const float* Wk = (const float*)d_in[2];
    const float* Wv = (const float*)d_in[3];
    __bf16* ws = (__bf16*)d_ws;
    float* out = (float*)d_out;

    wcvt_kernel<<<24, 256, 0, stream>>>(Wq, Wk, Wv, ws + WBF_OFF);
    proj_kernel<<<512, 256, 0, stream>>>(x, ws);
    attn_kernel<<<512, 256, 0, stream>>>(ws, out);
}

// Round 9
// 126.711 us; speedup vs baseline: 1.0290x; 1.0028x over previous
//
#include <hip/hip_runtime.h>
#include <hip/hip_bf16.h>

// Problem constants
#define BB 16
#define TT 2048
#define CC 128
#define HH 128
#define NQT128 16          // q tiles of 128 rows

typedef __bf16 bf16x8 __attribute__((ext_vector_type(8)));
typedef __bf16 bf16x4 __attribute__((ext_vector_type(4)));
typedef float  f32x4  __attribute__((ext_vector_type(4)));
typedef unsigned int u32x2 __attribute__((ext_vector_type(2)));

// ws layout (bf16 elems unless noted):
//   Qs  [b][tt16 128][ks 4][lane 64][j 8]   (exp2-domain scale folded)
//   Ks  [b][tt16 128][ks 4][lane 64][j 8]   (32-key tile = 8 KB contig)
//   Vs  [b][t32 64][h16 8][lane 64][j 8]    (32-key tile = 8 KB contig; h-halves
//                                            are the two 4 KB halves of a tile)
//   Wbf 3*128*128 FRAGMENT-SWIZZLED: [which][blk16 8][ks 4][lane 64][j 8]
#define BTH       ((size_t)BB * TT * HH)
#define WBF_OFF   (3 * BTH)

static __device__ __forceinline__ bf16x8 load_cvt8(const float* p) {
    float4 a = *(const float4*)p;
    float4 b = *(const float4*)(p + 4);
    bf16x8 r;
    r[0] = (__bf16)a.x; r[1] = (__bf16)a.y; r[2] = (__bf16)a.z; r[3] = (__bf16)a.w;
    r[4] = (__bf16)b.x; r[5] = (__bf16)b.y; r[6] = (__bf16)b.z; r[7] = (__bf16)b.w;
    return r;
}

// async global->LDS, 16 B/lane: data lands at lds_base + lane*16
static __device__ __forceinline__ void load_lds16(const void* g, void* l) {
    __builtin_amdgcn_global_load_lds(
        (const __attribute__((address_space(1))) unsigned int*)g,
        (__attribute__((address_space(3))) unsigned int*)l, 16, 0, 0);
}

// ---------------------------------------------------------------------------
// W pre-convert + FRAGMENT SWIZZLE (proj W loads become lane*16B coalesced).
// ---------------------------------------------------------------------------
__global__ __launch_bounds__(256) void wcvt_kernel(
    const float* __restrict__ Wq, const float* __restrict__ Wk,
    const float* __restrict__ Wv, __bf16* __restrict__ wbf)
{
    int idx = blockIdx.x * 256 + threadIdx.x;          // < 6144
    int which = idx >> 11;
    int rem = idx & 2047;
    int blk = rem >> 8;
    int r2  = rem & 255;
    int ks   = r2 >> 6;
    int lane = r2 & 63;
    int quad = lane >> 4, l16 = lane & 15;
    const float* src = (which == 0) ? Wq : (which == 1) ? Wk : Wv;
    float sc = (which == 0) ? (0.08838834764831845f * 1.4426950408889634f) : 1.0f;
    const float* p = src + (size_t)(blk * 16 + l16) * CC + ks * 32 + quad * 8;
    bf16x8 v;
    #pragma unroll
    for (int j = 0; j < 8; ++j) v[j] = (__bf16)(p[j] * sc);
    *(bf16x8*)(wbf + (size_t)which * 16384 + (((size_t)(blk * 4 + ks)) << 9) + lane * 8) = v;
}

// ---------------------------------------------------------------------------
// Projection, fully coalesced (x via padded LDS, W fragment-swizzled).
// ---------------------------------------------------------------------------
#define TR_QK 132
#define TR_V  68

__global__ __launch_bounds__(256) void proj_kernel(
    const float* __restrict__ x, __bf16* __restrict__ ws)
{
    __shared__ float  xs[64 * 132];
    __shared__ __bf16 tr[128 * TR_V];

    const int lane = threadIdx.x & 63;
    const int wave = threadIdx.x >> 6;
    const int quad = lane >> 4;
    const int l16  = lane & 15;
    const int tid  = threadIdx.x;
    const int m0 = blockIdx.x * 64;
    const int b  = m0 / TT;
    const int t0 = m0 % TT;

    const __bf16* Wbf = ws + WBF_OFF;
    __bf16* Qs = ws;
    __bf16* Ks = ws + BTH;
    __bf16* Vs = ws + 2 * BTH;

    const float* xg = x + (size_t)m0 * CC;
    #pragma unroll
    for (int t = 0; t < 8; ++t) {
        int f = t * 256 + tid;
        int row = f >> 5, c4 = f & 31;
        float4 v = *(const float4*)(xg + (size_t)f * 4);
        *(float4*)(&xs[row * 132 + c4 * 4]) = v;
    }
    __syncthreads();

    bf16x8 xf[4];
    #pragma unroll
    for (int ks = 0; ks < 4; ++ks)
        xf[ks] = load_cvt8(&xs[(wave * 16 + l16) * 132 + ks * 32 + quad * 8]);

    #pragma unroll
    for (int which = 0; which < 2; ++which) {
        const __bf16* Wb = Wbf + (size_t)which * 16384;
        __bf16* dst = which ? Ks : Qs;
        #pragma unroll
        for (int nt = 0; nt < 8; ++nt) {
            f32x4 acc = {0.f, 0.f, 0.f, 0.f};
            #pragma unroll
            for (int ks = 0; ks < 4; ++ks) {
                bf16x8 wf = *(const bf16x8*)(Wb + (((size_t)(nt * 4 + ks)) << 9) + lane * 8);
                acc = __builtin_amdgcn_mfma_f32_16x16x32_bf16(xf[ks], wf, acc, 0, 0, 0);
            }
            #pragma unroll
            for (int r = 0; r < 4; ++r)
                tr[(wave * 16 + quad * 4 + r) * TR_QK + nt * 16 + l16] = (__bf16)acc[r];
        }
        asm volatile("s_waitcnt lgkmcnt(0)" ::: "memory");
        #pragma unroll
        for (int ks = 0; ks < 4; ++ks) {
            const __bf16* p = &tr[(wave * 16 + l16) * TR_QK + ks * 32 + quad * 8];
            uint2 lo = *(const uint2*)p;
            uint2 hi = *(const uint2*)(p + 4);
            uint4 v; v.x = lo.x; v.y = lo.y; v.z = hi.x; v.w = hi.y;
            __bf16* o = dst + (((size_t)(b * 128 + t0 / 16 + wave) * 4 + ks) << 9) + lane * 8;
            *(uint4*)o = v;
        }
        asm volatile("s_waitcnt lgkmcnt(0)" ::: "memory");
    }

    __syncthreads();
    const __bf16* Wv = Wbf + 2 * 16384;
    #pragma unroll
    for (int msub = 0; msub < 8; ++msub) {
        f32x4 acc = {0.f, 0.f, 0.f, 0.f};
        #pragma unroll
        for (int ks = 0; ks < 4; ++ks) {
            bf16x8 wf = *(const bf16x8*)(Wv + (((size_t)(msub * 4 + ks)) << 9) + lane * 8);
            acc = __builtin_amdgcn_mfma_f32_16x16x32_bf16(wf, xf[ks], acc, 0, 0, 0);
        }
        #pragma unroll
        for (int r = 0; r < 4; ++r)
            tr[(msub * 16 + quad * 4 + r) * TR_V + wave * 16 + l16] = (__bf16)acc[r];
    }
    __syncthreads();
    #pragma unroll
    for (int i = 0; i < 4; ++i) {
        int t32 = i >> 1;
        int h16 = wave * 2 + (i & 1);
        const __bf16* p = &tr[(h16 * 16 + l16) * TR_V + t32 * 32 + quad * 8];
        uint2 lo = *(const uint2*)p;
        uint2 hi = *(const uint2*)(p + 4);
        uint4 v; v.x = lo.x; v.y = lo.y; v.z = hi.x; v.w = hi.y;
        __bf16* o = Vs + (((size_t)(b * 64 + t0 / 32 + t32) * 8 + h16) << 9) + lane * 8;
        *(uint4*)o = v;
    }
}

// ---------------------------------------------------------------------------
// BALANCED-PAIR flash attention — NO SPLIT-K, NO PARTIALS, NO REDUCE KERNEL.
// Round-8 structure (first clean-profiled: 55 us, occ 18.8/25 cap) + this
// round's single change: TRIPLE-BUFFERED staging with COUNTED vmcnt.
// Round-8 drained vmcnt(0) every 64-key interval after only ~500 cy of
// compute cover; each XCD serves ~4MB of K/V (2 batches) ~= its whole L2,
// so staging loads often miss to HBM (~900 cy) and the drain exposed that
// latency every interval (measured ~3900 cy/interval vs ~1000 compute).
// Now: prefetch depth 2 intervals, wait vmcnt(6) (next interval's 6 loads
// stay in flight), barrier BEFORE the new stage (the buffer it overwrites
// was last read in iter j-1; those ds_reads retired before the barrier).
//   8 pairs x 2 h x 2 m x 16 batches = 512 blocks (2/CU), 4 waves,
//   16 q-rows per wave; LDS 3 x 24576 = 73728 B (2 blocks/CU, = grid cap).
//  - swapped QK^T (mfma(K,Q) -> S^T); P redistribution in-register via
//    permlane32_swap + permlane16_swap.
//  - plain __launch_bounds__(256): forced waves/EU caps cause accumulator
//    spills (round-2 lesson). No device-scope fences (round-5 lesson).
// ---------------------------------------------------------------------------
__global__ __launch_bounds__(256) void attn_kernel(
    const __bf16* __restrict__ ws, float* __restrict__ outp)
{
    __shared__ char ldsBuf[3][24576];   // per buffer: K 2x8KB @0, V-half 2x4KB @16384

    const int lane = threadIdx.x & 63;
    const int wave = threadIdx.x >> 6;
    const int quad = lane >> 4;
    const int l16  = lane & 15;
    const int lane8 = lane * 8;
    const int lo16 = lane * 16;

    const int lin = blockIdx.x;                        // 512 blocks
    const int b   = (lin & 7) * 2 + ((lin >> 3) & 1);  // XCD-clustered batch
    const int rest = lin >> 4;                          // 0..31
    const int pid  = rest & 7;                          // pair 0..7
    const int hh0  = (rest >> 3) & 1;                   // head half
    const int mh   = 1 - (rest >> 4);                   // m-half (heavy mh=1 first)

    const __bf16* Qs = ws;
    const __bf16* Ks = ws + BTH;
    const __bf16* Vs = ws + 2 * BTH;

    // staging pointers (per-wave chunk bases)
    const char* kg = (const char*)Ks + (size_t)b * 524288 + wave * 4096 + lo16;
    const char* vg = (const char*)Vs + (size_t)b * 524288 + hh0 * 4096 + wave * 1024 + lo16;

    // stage one 64-key step j into buffer BUF: K 16KB (4 chunks/wave) + V 8KB
    #define STAGE64(J, BUF)                                                     \
        do {                                                                    \
            char* dK_ = ldsBuf[BUF] + wave * 4096;                              \
            char* dV_ = ldsBuf[BUF] + 16384 + wave * 1024;                      \
            const char* sk_ = kg + (size_t)(J) * 16384;                         \
            _Pragma("unroll")                                                   \
            for (int c_ = 0; c_ < 4; ++c_)                                      \
                load_lds16(sk_ + c_ * 1024, dK_ + c_ * 1024);                   \
            _Pragma("unroll")                                                   \
            for (int h_ = 0; h_ < 2; ++h_)                                      \
                load_lds16(vg + (size_t)(2 * (J) + h_) * 8192, dV_ + h_ * 4096);\
        } while (0)

    #pragma unroll 1
    for (int pass = 0; pass < 2; ++pass) {
        const int qt = pass ? (15 - pid) : pid;
        const int qw = qt * 128 + mh * 64 + wave * 16;     // wave's 16 q rows
        const int ttw = (qw >> 5) + 1;                     // wave causal clamp (32-key tiles)
        const int nj  = 2 * qt + mh + 1;                   // 64-key intervals

        // Q fragments (single m)
        bf16x8 qf[4];
        #pragma unroll
        for (int ks = 0; ks < 4; ++ks)
            qf[ks] = *(const bf16x8*)(Qs + (((size_t)(b * 128 + qt * 8 + mh * 4 + wave) * 4 + ks) << 9) + lane8);

        float l_r = 0.f;
        f32x4 o[4];
        #pragma unroll
        for (int h8 = 0; h8 < 4; ++h8) o[h8] = (f32x4){0.f, 0.f, 0.f, 0.f};

        // prologue: 2 intervals in flight
        STAGE64(0, 0);
        if (1 < nj) STAGE64(1, 1);

        int cur = 0;                                       // buffer of interval j
        for (int j = 0; j < nj; ++j) {
            // counted wait: interval j's 6 loads done; j+1's 6 stay in flight
            if (j + 1 < nj) {
                asm volatile("s_waitcnt vmcnt(6)" ::: "memory");
            } else {
                asm volatile("s_waitcnt vmcnt(0)" ::: "memory");
            }
            __builtin_amdgcn_s_barrier();
            // stage j+2 into the buffer last read at iter j-1 (reads retired
            // before the barrier above) -> race-free, depth-2 prefetch
            if (j + 2 < nj) {
                int c2 = cur + 2; if (c2 >= 3) c2 -= 3;
                STAGE64(j + 2, c2);
            }

            #pragma unroll
            for (int half = 0; half < 2; ++half) {
                const int tt = 2 * j + half;
                if (tt >= ttw) continue;
                const char* lk = ldsBuf[cur] + half * 8192;
                const char* lv = ldsBuf[cur] + 16384 + half * 4096;

                // ---- S^T = K Q^T (lane holds 4 consecutive keys for q=l16) --
                f32x4 s2[2];
                #pragma unroll
                for (int nsub = 0; nsub < 2; ++nsub) {
                    bf16x8 kfr[4];
                    #pragma unroll
                    for (int ks = 0; ks < 4; ++ks)
                        kfr[ks] = *(const bf16x8*)(lk + ((nsub * 4 + ks) << 10) + lo16);
                    f32x4 a2 = {0.f, 0.f, 0.f, 0.f};
                    __builtin_amdgcn_s_setprio(1);
                    #pragma unroll
                    for (int ks = 0; ks < 4; ++ks)
                        a2 = __builtin_amdgcn_mfma_f32_16x16x32_bf16(kfr[ks], qf[ks], a2, 0, 0, 0);
                    __builtin_amdgcn_s_setprio(0);
                    s2[nsub] = a2;
                }

                const int k0 = tt * 32;
                // ---- mask + exp2 + lane-local l; pack P into dwords --------
                unsigned int du[2][2];
                const int qrow = qw + l16;
                if (k0 + 31 > qw) {                        // boundary tile (uniform)
                    #pragma unroll
                    for (int nsub = 0; nsub < 2; ++nsub) {
                        const int kb = k0 + nsub * 16 + quad * 4;
                        union { bf16x4 v; unsigned int u[2]; } cv;
                        #pragma unroll
                        for (int r = 0; r < 4; ++r) {
                            float sv = (kb + r > qrow) ? -3e38f : s2[nsub][r];
                            float p = __builtin_amdgcn_exp2f(sv);
                            l_r += p;
                            cv.v[r] = (__bf16)p;
                        }
                        du[nsub][0] = cv.u[0];
                        du[nsub][1] = cv.u[1];
                    }
                } else {
                    #pragma unroll
                    for (int nsub = 0; nsub < 2; ++nsub) {
                        union { bf16x4 v; unsigned int u[2]; } cv;
                        #pragma unroll
                        for (int r = 0; r < 4; ++r) {
                            float p = __builtin_amdgcn_exp2f(s2[nsub][r]);
                            l_r += p;
                            cv.v[r] = (__bf16)p;
                        }
                        du[nsub][0] = cv.u[0];
                        du[nsub][1] = cv.u[1];
                    }
                }

                // ---- P: C-layout -> A-layout fully in-register -------------
                bf16x8 pf;
                {
                    union { unsigned int u[4]; bf16x8 v; } cc;
                    #pragma unroll
                    for (int h = 0; h < 2; ++h) {
                        u32x2 t1 = __builtin_amdgcn_permlane32_swap(
                            du[0][h], du[1][h], false, false);
                        u32x2 t2 = __builtin_amdgcn_permlane16_swap(
                            t1[0], t1[1], false, false);
                        cc.u[h]     = t2[0];
                        cc.u[2 + h] = t2[1];
                    }
                    pf = cc.v;
                }

                // ---- O += P V (k = 32) over this block's 4 h16 columns -----
                __builtin_amdgcn_s_setprio(1);
                #pragma unroll
                for (int h8 = 0; h8 < 4; ++h8) {
                    bf16x8 v0 = *(const bf16x8*)(lv + (h8 << 10) + lo16);
                    o[h8] = __builtin_amdgcn_mfma_f32_16x16x32_bf16(pf, v0, o[h8], 0, 0, 0);
                }
                __builtin_amdgcn_s_setprio(0);
            }
            cur = (cur + 1 == 3) ? 0 : cur + 1;
        }

        // ---- normalize + direct write (per-wave) ---------------------------
        l_r += __shfl_xor(l_r, 16, 64);
        l_r += __shfl_xor(l_r, 32, 64);
        float inv[4];
        #pragma unroll
        for (int r = 0; r < 4; ++r)
            inv[r] = 1.0f / __shfl(l_r, (lane & 48) | (quad * 4 + r), 64);
        #pragma unroll
        for (int h8 = 0; h8 < 4; ++h8)
            #pragma unroll
            for (int r = 0; r < 4; ++r)
                outp[(size_t)(b * TT + qw + quad * 4 + r) * HH + hh0 * 64 + h8 * 16 + l16] = o[h8][r] * inv[r];

        // make pass-2 prologue staging safe: all waves' reads of all buffers
        // from this pass must be retired before buf0/buf1 are overwritten
        __builtin_amdgcn_s_barrier();
    }
    #undef STAGE64
}

extern "C" void kernel_launch(void* const* d_in, const int* in_sizes, int n_in,
                              void* d_out, int out_size, void* d_ws, size_t ws_size,
                              hipStream_t stream)
{
    const float* x  = (const float*)d_in[0];
    const float* Wq = (const float*)d_in[1];
    const float* Wk = (const float*)d_in[2];
    const float* Wv = (const float*)d_in[3];
    __bf16* ws = (__bf16*)d_ws;
    float* out = (float*)d_out;

    wcvt_kernel<<<24, 256, 0, stream>>>(Wq, Wk, Wv, ws + WBF_OFF);
    proj_kernel<<<512, 256, 0, stream>>>(x, ws);
    attn_kernel<<<512, 256, 0, stream>>>(ws, out);
}

// Round 10
// 123.668 us; speedup vs baseline: 1.0543x; 1.0246x over previous
//
#include <hip/hip_runtime.h>
#include <hip/hip_bf16.h>

// Problem constants
#define BB 16
#define TT 2048
#define CC 128
#define HH 128
#define NQT128 16          // q tiles of 128 rows

typedef __bf16 bf16x8 __attribute__((ext_vector_type(8)));
typedef __bf16 bf16x4 __attribute__((ext_vector_type(4)));
typedef float  f32x4  __attribute__((ext_vector_type(4)));
typedef unsigned int u32x2 __attribute__((ext_vector_type(2)));

// ws layout (bf16 elems unless noted):
//   Qs  [b][tt16 128][ks 4][lane 64][j 8]   (exp2-domain scale folded)
//   Ks  [b][tt16 128][ks 4][lane 64][j 8]   (32-key tile = 8 KB contig)
//   Vs  [b][t32 64][h16 8][lane 64][j 8]    (32-key tile = 8 KB contig)
//   Wbf 3*128*128 FRAGMENT-SWIZZLED: [which][blk16 8][ks 4][lane 64][j 8]
#define BTH       ((size_t)BB * TT * HH)
#define WBF_OFF   (3 * BTH)

static __device__ __forceinline__ bf16x8 load_cvt8(const float* p) {
    float4 a = *(const float4*)p;
    float4 b = *(const float4*)(p + 4);
    bf16x8 r;
    r[0] = (__bf16)a.x; r[1] = (__bf16)a.y; r[2] = (__bf16)a.z; r[3] = (__bf16)a.w;
    r[4] = (__bf16)b.x; r[5] = (__bf16)b.y; r[6] = (__bf16)b.z; r[7] = (__bf16)b.w;
    return r;
}

// async global->LDS, 16 B/lane: data lands at lds_base + lane*16
static __device__ __forceinline__ void load_lds16(const void* g, void* l) {
    __builtin_amdgcn_global_load_lds(
        (const __attribute__((address_space(1))) unsigned int*)g,
        (__attribute__((address_space(3))) unsigned int*)l, 16, 0, 0);
}

// ---------------------------------------------------------------------------
// W pre-convert + FRAGMENT SWIZZLE (proj W loads become lane*16B coalesced).
// ---------------------------------------------------------------------------
__global__ __launch_bounds__(256) void wcvt_kernel(
    const float* __restrict__ Wq, const float* __restrict__ Wk,
    const float* __restrict__ Wv, __bf16* __restrict__ wbf)
{
    int idx = blockIdx.x * 256 + threadIdx.x;          // < 6144
    int which = idx >> 11;
    int rem = idx & 2047;
    int blk = rem >> 8;
    int r2  = rem & 255;
    int ks   = r2 >> 6;
    int lane = r2 & 63;
    int quad = lane >> 4, l16 = lane & 15;
    const float* src = (which == 0) ? Wq : (which == 1) ? Wk : Wv;
    float sc = (which == 0) ? (0.08838834764831845f * 1.4426950408889634f) : 1.0f;
    const float* p = src + (size_t)(blk * 16 + l16) * CC + ks * 32 + quad * 8;
    bf16x8 v;
    #pragma unroll
    for (int j = 0; j < 8; ++j) v[j] = (__bf16)(p[j] * sc);
    *(bf16x8*)(wbf + (size_t)which * 16384 + (((size_t)(blk * 4 + ks)) << 9) + lane * 8) = v;
}

// ---------------------------------------------------------------------------
// Projection, fully coalesced (x via padded LDS, W fragment-swizzled).
// ---------------------------------------------------------------------------
#define TR_QK 132
#define TR_V  68

__global__ __launch_bounds__(256) void proj_kernel(
    const float* __restrict__ x, __bf16* __restrict__ ws)
{
    __shared__ float  xs[64 * 132];
    __shared__ __bf16 tr[128 * TR_V];

    const int lane = threadIdx.x & 63;
    const int wave = threadIdx.x >> 6;
    const int quad = lane >> 4;
    const int l16  = lane & 15;
    const int tid  = threadIdx.x;
    const int m0 = blockIdx.x * 64;
    const int b  = m0 / TT;
    const int t0 = m0 % TT;

    const __bf16* Wbf = ws + WBF_OFF;
    __bf16* Qs = ws;
    __bf16* Ks = ws + BTH;
    __bf16* Vs = ws + 2 * BTH;

    const float* xg = x + (size_t)m0 * CC;
    #pragma unroll
    for (int t = 0; t < 8; ++t) {
        int f = t * 256 + tid;
        int row = f >> 5, c4 = f & 31;
        float4 v = *(const float4*)(xg + (size_t)f * 4);
        *(float4*)(&xs[row * 132 + c4 * 4]) = v;
    }
    __syncthreads();

    bf16x8 xf[4];
    #pragma unroll
    for (int ks = 0; ks < 4; ++ks)
        xf[ks] = load_cvt8(&xs[(wave * 16 + l16) * 132 + ks * 32 + quad * 8]);

    #pragma unroll
    for (int which = 0; which < 2; ++which) {
        const __bf16* Wb = Wbf + (size_t)which * 16384;
        __bf16* dst = which ? Ks : Qs;
        #pragma unroll
        for (int nt = 0; nt < 8; ++nt) {
            f32x4 acc = {0.f, 0.f, 0.f, 0.f};
            #pragma unroll
            for (int ks = 0; ks < 4; ++ks) {
                bf16x8 wf = *(const bf16x8*)(Wb + (((size_t)(nt * 4 + ks)) << 9) + lane * 8);
                acc = __builtin_amdgcn_mfma_f32_16x16x32_bf16(xf[ks], wf, acc, 0, 0, 0);
            }
            #pragma unroll
            for (int r = 0; r < 4; ++r)
                tr[(wave * 16 + quad * 4 + r) * TR_QK + nt * 16 + l16] = (__bf16)acc[r];
        }
        asm volatile("s_waitcnt lgkmcnt(0)" ::: "memory");
        #pragma unroll
        for (int ks = 0; ks < 4; ++ks) {
            const __bf16* p = &tr[(wave * 16 + l16) * TR_QK + ks * 32 + quad * 8];
            uint2 lo = *(const uint2*)p;
            uint2 hi = *(const uint2*)(p + 4);
            uint4 v; v.x = lo.x; v.y = lo.y; v.z = hi.x; v.w = hi.y;
            __bf16* o = dst + (((size_t)(b * 128 + t0 / 16 + wave) * 4 + ks) << 9) + lane * 8;
            *(uint4*)o = v;
        }
        asm volatile("s_waitcnt lgkmcnt(0)" ::: "memory");
    }

    __syncthreads();
    const __bf16* Wv = Wbf + 2 * 16384;
    #pragma unroll
    for (int msub = 0; msub < 8; ++msub) {
        f32x4 acc = {0.f, 0.f, 0.f, 0.f};
        #pragma unroll
        for (int ks = 0; ks < 4; ++ks) {
            bf16x8 wf = *(const bf16x8*)(Wv + (((size_t)(msub * 4 + ks)) << 9) + lane * 8);
            acc = __builtin_amdgcn_mfma_f32_16x16x32_bf16(wf, xf[ks], acc, 0, 0, 0);
        }
        #pragma unroll
        for (int r = 0; r < 4; ++r)
            tr[(msub * 16 + quad * 4 + r) * TR_V + wave * 16 + l16] = (__bf16)acc[r];
    }
    __syncthreads();
    #pragma unroll
    for (int i = 0; i < 4; ++i) {
        int t32 = i >> 1;
        int h16 = wave * 2 + (i & 1);
        const __bf16* p = &tr[(h16 * 16 + l16) * TR_V + t32 * 32 + quad * 8];
        uint2 lo = *(const uint2*)p;
        uint2 hi = *(const uint2*)(p + 4);
        uint4 v; v.x = lo.x; v.y = lo.y; v.z = hi.x; v.w = hi.y;
        __bf16* o = Vs + (((size_t)(b * 64 + t0 / 32 + t32) * 8 + h16) << 9) + lane * 8;
        *(uint4*)o = v;
    }
}

// ---------------------------------------------------------------------------
// Flash attention, 2-WAVE BLOCKS, no h-split, no partials, no reduce kernel.
// Round-9 post-mortem: 51 us at 2 waves/SIMD was dependency-stall-bound and
// the h-half split computed QK+softmax twice per output. This version:
//  - block = one 32-row q-slice (kq = 0..63) x batch: 1024 blocks x 128 thr.
//    Each wave owns 16 q-rows; both waves share the staged K/V tile. The
//    32-row slice spans exactly one 32-key boundary tile -> no divergence.
//  - QK computed ONCE per output (MFMA total -33%, softmax VALU -50% vs r9);
//    PV over all 8 h16 columns (o[8]).
//  - 4 blocks/CU resident (LDS 32KB, grid 1024): 8 waves/CU in 4 INDEPENDENT
//    2-wave barrier groups -> always another unblocked block to issue from.
//  - wave0 stages K (8x1KB), wave1 stages V; counted vmcnt(8) two-barrier
//    loop (round-3 proven): stage(tt+1) issued before the top barrier, never
//    drained mid-loop.
//  - swapped QK^T (mfma(K,Q) -> S^T); P redistribution in-register via
//    permlane32_swap + permlane16_swap.
//  - heavy chains first (kq descending), XCD-clustered batches (lin&7=XCD).
//  - no forced waves/EU cap (round-2 spill lesson); no device fences (r5).
// ---------------------------------------------------------------------------
__global__ __launch_bounds__(128) void attn_kernel(
    const __bf16* __restrict__ ws, float* __restrict__ outp)
{
    __shared__ char ldsBuf[2][16384];   // per buffer: K 8KB @0, V 8KB @8192

    const int lane = threadIdx.x & 63;
    const int wave = threadIdx.x >> 6;                 // 0..1
    const int quad = lane >> 4;
    const int l16  = lane & 15;
    const int lane8 = lane * 8;
    const int lo16 = lane * 16;

    const int lin = blockIdx.x;                        // 1024 blocks
    const int b   = (lin & 7) * 2 + ((lin >> 3) & 1);  // XCD-clustered batch
    const int kq  = 63 - (lin >> 4);                   // heavy chains first
    const int qw  = kq * 32 + wave * 16;               // wave's 16 q rows
    const int nt  = kq + 1;                            // causal 32-key tiles

    const __bf16* Qs = ws;
    const __bf16* Ks = ws + BTH;
    const __bf16* Vs = ws + 2 * BTH;

    // Q fragments (row16 block = 2*kq + wave)
    bf16x8 qf[4];
    #pragma unroll
    for (int ks = 0; ks < 4; ++ks)
        qf[ks] = *(const bf16x8*)(Qs + (((size_t)(b * 128 + 2 * kq + wave) * 4 + ks) << 9) + lane8);

    float l_r = 0.f;
    f32x4 o[8];
    #pragma unroll
    for (int h8 = 0; h8 < 8; ++h8) o[h8] = (f32x4){0.f, 0.f, 0.f, 0.f};

    // staging: wave0 streams K, wave1 streams V (8 x 1KB chunks per tile)
    const char* sbase = (wave ? (const char*)Vs : (const char*)Ks)
                        + (size_t)b * 524288 + lo16;

    #define STAGE(TTv, BUF)                                        \
        do {                                                       \
            const char* s_ = sbase + ((size_t)(TTv) << 13);        \
            char* d_ = ldsBuf[BUF] + wave * 8192;                  \
            _Pragma("unroll")                                      \
            for (int c_ = 0; c_ < 8; ++c_)                         \
                load_lds16(s_ + c_ * 1024, d_ + c_ * 1024);        \
        } while (0)

    STAGE(0, 0);

    for (int tt = 0; tt < nt; ++tt) {
        const int cur = tt & 1;
        // issue next-tile DMA, then counted wait: only stage(tt) must land
        if (tt + 1 < nt) {
            STAGE(tt + 1, cur ^ 1);
            asm volatile("s_waitcnt vmcnt(8)" ::: "memory");
        } else {
            asm volatile("s_waitcnt vmcnt(0)" ::: "memory");
        }
        __builtin_amdgcn_s_barrier();      // stage(tt) visible to both waves

        const char* lk = ldsBuf[cur];
        const char* lv = ldsBuf[cur] + 8192;

        // ---- S^T = K Q^T (lane holds 4 consecutive keys for q-row l16) ----
        f32x4 s2[2];
        #pragma unroll
        for (int nsub = 0; nsub < 2; ++nsub) {
            bf16x8 kfr[4];
            #pragma unroll
            for (int ks = 0; ks < 4; ++ks)
                kfr[ks] = *(const bf16x8*)(lk + ((nsub * 4 + ks) << 10) + lo16);
            f32x4 a2 = {0.f, 0.f, 0.f, 0.f};
            __builtin_amdgcn_s_setprio(1);
            #pragma unroll
            for (int ks = 0; ks < 4; ++ks)
                a2 = __builtin_amdgcn_mfma_f32_16x16x32_bf16(kfr[ks], qf[ks], a2, 0, 0, 0);
            __builtin_amdgcn_s_setprio(0);
            s2[nsub] = a2;
        }

        const int k0 = tt * 32;
        // ---- mask (last tile only) + exp2 + lane-local l; pack P ----------
        unsigned int du[2][2];
        if (tt == nt - 1) {                            // boundary tile (uniform)
            const int qrow = qw + l16;
            #pragma unroll
            for (int nsub = 0; nsub < 2; ++nsub) {
                const int kb = k0 + nsub * 16 + quad * 4;
                union { bf16x4 v; unsigned int u[2]; } cv;
                #pragma unroll
                for (int r = 0; r < 4; ++r) {
                    float sv = (kb + r > qrow) ? -3e38f : s2[nsub][r];
                    float p = __builtin_amdgcn_exp2f(sv);
                    l_r += p;
                    cv.v[r] = (__bf16)p;
                }
                du[nsub][0] = cv.u[0];
                du[nsub][1] = cv.u[1];
            }
        } else {
            #pragma unroll
            for (int nsub = 0; nsub < 2; ++nsub) {
                union { bf16x4 v; unsigned int u[2]; } cv;
                #pragma unroll
                for (int r = 0; r < 4; ++r) {
                    float p = __builtin_amdgcn_exp2f(s2[nsub][r]);
                    l_r += p;
                    cv.v[r] = (__bf16)p;
                }
                du[nsub][0] = cv.u[0];
                du[nsub][1] = cv.u[1];
            }
        }

        // ---- P: C-layout -> A-layout fully in-register --------------------
        bf16x8 pf;
        {
            union { unsigned int u[4]; bf16x8 v; } cc;
            #pragma unroll
            for (int h = 0; h < 2; ++h) {
                u32x2 t1 = __builtin_amdgcn_permlane32_swap(
                    du[0][h], du[1][h], false, false);
                u32x2 t2 = __builtin_amdgcn_permlane16_swap(
                    t1[0], t1[1], false, false);
                cc.u[h]     = t2[0];
                cc.u[2 + h] = t2[1];
            }
            pf = cc.v;
        }

        // ---- O += P V (k = 32) over all 8 h16 columns ---------------------
        __builtin_amdgcn_s_setprio(1);
        #pragma unroll
        for (int h8 = 0; h8 < 8; ++h8) {
            bf16x8 v0 = *(const bf16x8*)(lv + (h8 << 10) + lo16);
            o[h8] = __builtin_amdgcn_mfma_f32_16x16x32_bf16(pf, v0, o[h8], 0, 0, 0);
        }
        __builtin_amdgcn_s_setprio(0);

        // both waves' LDS reads of buf cur retired before it is restaged
        asm volatile("s_waitcnt lgkmcnt(0)" ::: "memory");
        __builtin_amdgcn_s_barrier();
    }
    #undef STAGE

    // ---- normalize + direct write (per-wave) ------------------------------
    l_r += __shfl_xor(l_r, 16, 64);
    l_r += __shfl_xor(l_r, 32, 64);
    float inv[4];
    #pragma unroll
    for (int r = 0; r < 4; ++r)
        inv[r] = 1.0f / __shfl(l_r, (lane & 48) | (quad * 4 + r), 64);
    #pragma unroll
    for (int h8 = 0; h8 < 8; ++h8)
        #pragma unroll
        for (int r = 0; r < 4; ++r)
            outp[(size_t)(b * TT + qw + quad * 4 + r) * HH + h8 * 16 + l16] = o[h8][r] * inv[r];
}

extern "C" void kernel_launch(void* const* d_in, const int* in_sizes, int n_in,
                              void* d_out, int out_size, void* d_ws, size_t ws_size,
                              hipStream_t stream)
{
    const float* x  = (const float*)d_in[0];
    const float* Wq = (const float*)d_in[1];
    const float* Wk = (const float*)d_in[2];
    const float* Wv = (const float*)d_in[3];
    __bf16* ws = (__bf16*)d_ws;
    float* out = (float*)d_out;

    wcvt_kernel<<<24, 256, 0, stream>>>(Wq, Wk, Wv, ws + WBF_OFF);
    proj_kernel<<<512, 256, 0, stream>>>(x, ws);
    attn_kernel<<<1024, 128, 0, stream>>>(ws, out);
}